// Round 1
// baseline (199.771 us; speedup 1.0000x reference)
//
#include <hip/hip_runtime.h>
#include <hip/hip_bf16.h>

#define Bsz 4
#define Ssz 2048
#define Dsz 512
#define Hsz 8
#define DKsz 64

typedef __bf16 bf16x8 __attribute__((ext_vector_type(8)));
typedef float f32x4 __attribute__((ext_vector_type(4)));

__device__ inline bf16x8 cvt_bf16x8(const float4& a, const float4& b) {
    bf16x8 r;
    r[0] = (__bf16)a.x; r[1] = (__bf16)a.y; r[2] = (__bf16)a.z; r[3] = (__bf16)a.w;
    r[4] = (__bf16)b.x; r[5] = (__bf16)b.y; r[6] = (__bf16)b.z; r[7] = (__bf16)b.w;
    return r;
}

// y = x @ W^T for W in {Wq,Wk,Wv} (selected by blockIdx.z).
// Q,K written as bf16 [B,H,S,DK]; V written transposed as bf16 [B,H,DK,S].
__global__ __launch_bounds__(256) void qkv_proj_kernel(
    const float* __restrict__ x, const float* __restrict__ Wq,
    const float* __restrict__ Wk, const float* __restrict__ Wv,
    __bf16* __restrict__ Qo, __bf16* __restrict__ Ko, __bf16* __restrict__ Vo)
{
    __shared__ __bf16 xs[64][72];   // +8 pad: keeps 16B align, kills bank conflicts
    __shared__ __bf16 wsh[64][72];

    const int tid  = threadIdx.x;
    const int lane = tid & 63;
    const int wave = tid >> 6;
    const int quad = lane >> 4;
    const int l16  = lane & 15;

    const int tm = blockIdx.x * 64;           // m tile (row of x, flat b*S+s)
    const int tn = blockIdx.y * 64;           // n tile (output feature)
    const int which = blockIdx.z;             // 0=Q 1=K 2=V
    const float* W = (which == 0) ? Wq : (which == 1) ? Wk : Wv;

    const int srow = tid >> 2;                // 0..63
    const int scol = (tid & 3) * 16;          // 0,16,32,48

    f32x4 acc[4];
    #pragma unroll
    for (int i = 0; i < 4; ++i) acc[i] = (f32x4){0.f, 0.f, 0.f, 0.f};

    for (int k0 = 0; k0 < Dsz; k0 += 64) {
        const float4* xr = (const float4*)(x + (size_t)(tm + srow) * Dsz + k0 + scol);
        const float4* wr = (const float4*)(W + (size_t)(tn + srow) * Dsz + k0 + scol);
        float4 x0 = xr[0], x1 = xr[1], x2 = xr[2], x3 = xr[3];
        float4 w0 = wr[0], w1 = wr[1], w2 = wr[2], w3 = wr[3];
        *(bf16x8*)&xs[srow][scol]      = cvt_bf16x8(x0, x1);
        *(bf16x8*)&xs[srow][scol + 8]  = cvt_bf16x8(x2, x3);
        *(bf16x8*)&wsh[srow][scol]     = cvt_bf16x8(w0, w1);
        *(bf16x8*)&wsh[srow][scol + 8] = cvt_bf16x8(w2, w3);
        __syncthreads();

        #pragma unroll
        for (int kk = 0; kk < 2; ++kk) {
            // A-frag: A[m=l16][k=quad*8+j]
            bf16x8 a = *(const bf16x8*)&xs[wave * 16 + l16][kk * 32 + quad * 8];
            #pragma unroll
            for (int ns = 0; ns < 4; ++ns) {
                // B-frag: B[k][n] = W[n][k] -> contiguous along k
                bf16x8 b = *(const bf16x8*)&wsh[ns * 16 + l16][kk * 32 + quad * 8];
                acc[ns] = __builtin_amdgcn_mfma_f32_16x16x32_bf16(a, b, acc[ns], 0, 0, 0);
            }
        }
        __syncthreads();
    }

    // C/D layout: col = l16, row = quad*4 + r
    #pragma unroll
    for (int ns = 0; ns < 4; ++ns) {
        const int n = tn + ns * 16 + l16;
        const int h = n >> 6, d = n & 63;
        #pragma unroll
        for (int r = 0; r < 4; ++r) {
            const int m = tm + wave * 16 + quad * 4 + r;
            const int b = m >> 11, s = m & (Ssz - 1);
            const float v = acc[ns][r];
            if (which == 0)
                Qo[((((size_t)b * Hsz + h) * Ssz + s) << 6) + d] = (__bf16)v;
            else if (which == 1)
                Ko[((((size_t)b * Hsz + h) * Ssz + s) << 6) + d] = (__bf16)v;
            else
                Vo[(((size_t)b * Hsz + h) * DKsz + d) * Ssz + s] = (__bf16)v;
        }
    }
}

// Flash-style attention, no max-subtraction (faithful to reference's plain exp).
// Block: 4 waves, 64 q-rows of one (b,h). Loop over 64-wide K/V tiles.
__global__ __launch_bounds__(256) void attn_kernel(
    const __bf16* __restrict__ Q, const __bf16* __restrict__ K,
    const __bf16* __restrict__ VT, float* __restrict__ out)
{
    __shared__ __bf16 ks[64][72];        // K[s_local][dk]
    __shared__ __bf16 vs[64][72];        // V^T[dk][s_local]
    __shared__ __bf16 ps[4][16][72];     // per-wave P tile (C-layout -> A-layout)

    const int tid  = threadIdx.x;
    const int lane = tid & 63;
    const int wave = tid >> 6;
    const int quad = lane >> 4;
    const int l16  = lane & 15;

    const int qt = blockIdx.x;           // 64-row q tile
    const int bh = blockIdx.y;
    const int b  = bh >> 3;
    const int h  = bh & 7;

    const __bf16* Qb = Q  + (size_t)bh * Ssz * DKsz;
    const __bf16* Kb = K  + (size_t)bh * Ssz * DKsz;
    const __bf16* Vb = VT + (size_t)bh * DKsz * Ssz;

    // Q fragments live in registers for the whole kernel
    bf16x8 qf[2];
    {
        const __bf16* qrow = Qb + (size_t)(qt * 64 + wave * 16 + l16) * DKsz;
        qf[0] = *(const bf16x8*)(qrow + quad * 8);
        qf[1] = *(const bf16x8*)(qrow + 32 + quad * 8);
    }

    f32x4 oacc[4];
    #pragma unroll
    for (int i = 0; i < 4; ++i) oacc[i] = (f32x4){0.f, 0.f, 0.f, 0.f};
    float lsum[4] = {0.f, 0.f, 0.f, 0.f};

    const int srow = tid >> 2;           // 0..63
    const int sc   = (tid & 3) * 8;      // 0,8,16,24

    for (int kb = 0; kb < Ssz; kb += 64) {
        const __bf16* krow = Kb + (size_t)(kb + srow) * DKsz;
        const __bf16* vrow = Vb + (size_t)srow * Ssz + kb;
        bf16x8 k0 = *(const bf16x8*)(krow + sc);
        bf16x8 k1 = *(const bf16x8*)(krow + 32 + sc);
        bf16x8 v0 = *(const bf16x8*)(vrow + sc);
        bf16x8 v1 = *(const bf16x8*)(vrow + 32 + sc);
        *(bf16x8*)&ks[srow][sc]      = k0;
        *(bf16x8*)&ks[srow][32 + sc] = k1;
        *(bf16x8*)&vs[srow][sc]      = v0;
        *(bf16x8*)&vs[srow][32 + sc] = v1;
        __syncthreads();

        // S = Q K^T ; P = exp(S * 1/8); accumulate row sums; stash P in LDS
        #pragma unroll
        for (int ns = 0; ns < 4; ++ns) {
            f32x4 sacc = (f32x4){0.f, 0.f, 0.f, 0.f};
            #pragma unroll
            for (int kk = 0; kk < 2; ++kk) {
                bf16x8 bfr = *(const bf16x8*)&ks[ns * 16 + l16][kk * 32 + quad * 8];
                sacc = __builtin_amdgcn_mfma_f32_16x16x32_bf16(qf[kk], bfr, sacc, 0, 0, 0);
            }
            #pragma unroll
            for (int r = 0; r < 4; ++r) {
                float p = __expf(sacc[r] * 0.125f);
                lsum[r] += p;
                ps[wave][quad * 4 + r][ns * 16 + l16] = (__bf16)p;
            }
        }
        __syncthreads();

        // O += P V  (A = P from LDS in A-layout, B = V via VT rows, contiguous)
        #pragma unroll
        for (int kk = 0; kk < 2; ++kk) {
            bf16x8 af = *(const bf16x8*)&ps[wave][l16][kk * 32 + quad * 8];
            #pragma unroll
            for (int ns = 0; ns < 4; ++ns) {
                bf16x8 bfr = *(const bf16x8*)&vs[ns * 16 + l16][kk * 32 + quad * 8];
                oacc[ns] = __builtin_amdgcn_mfma_f32_16x16x32_bf16(af, bfr, oacc[ns], 0, 0, 0);
            }
        }
        __syncthreads();
    }

    // reduce row sums across the 16 lanes of each quad (cols of the row)
    #pragma unroll
    for (int r = 0; r < 4; ++r) {
        float v = lsum[r];
        v += __shfl_xor(v, 1);
        v += __shfl_xor(v, 2);
        v += __shfl_xor(v, 4);
        v += __shfl_xor(v, 8);
        lsum[r] = 1.f / (v + 1e-8f);
    }

    // write out [B,S,D] fp32
    #pragma unroll
    for (int ns = 0; ns < 4; ++ns) {
        const int d = ns * 16 + l16;
        #pragma unroll
        for (int r = 0; r < 4; ++r) {
            const int s = qt * 64 + wave * 16 + quad * 4 + r;
            out[((size_t)b * Ssz + s) * Dsz + h * DKsz + d] = oacc[ns][r] * lsum[r];
        }
    }
}

extern "C" void kernel_launch(void* const* d_in, const int* in_sizes, int n_in,
                              void* d_out, int out_size, void* d_ws, size_t ws_size,
                              hipStream_t stream) {
    const float* x  = (const float*)d_in[0];
    const float* Wq = (const float*)d_in[1];
    const float* Wk = (const float*)d_in[2];
    const float* Wv = (const float*)d_in[3];
    float* out = (float*)d_out;

    const size_t per = (size_t)Bsz * Hsz * Ssz * DKsz;  // 4M elements each
    __bf16* Qw = (__bf16*)d_ws;
    __bf16* Kw = Qw + per;
    __bf16* Vw = Kw + per;

    qkv_proj_kernel<<<dim3((Bsz * Ssz) / 64, Dsz / 64, 3), 256, 0, stream>>>(
        x, Wq, Wk, Wv, Qw, Kw, Vw);
    attn_kernel<<<dim3(Ssz / 64, Bsz * Hsz), 256, 0, stream>>>(Qw, Kw, Vw, out);
}